// Round 17
// baseline (2926.527 us; speedup 1.0000x reference)
//
#include <hip/hip_runtime.h>
#include <math.h>

#define B_ROWS 32768
#define DIM    1024
#define PAD    132
#define PB2    144            // B rows: 128 cols + swizzle gaps (col' = col + 4*(col>>5) <= 139)
#define LDSF   (2*32*PAD + 2*32*PB2)   // 17664 floats = 70.7 KB (>= 16384 exchange floats)

// Numerics contract (verified r10-r16, absmax 0.0): BLIS sgemm, KC=512.
// Per C element: p1 = serial ascending FMA chain k=0..511, p2 = k=512..1023,
// C = fl(p1+p2). Panels split across the two 256-thread halves of a
// 512-thread block; combined via LDS exchange at the end.
//
// r16 model: LDS read pipe is the wall: 768 cyc/kk/CU conflict-free vs 512
// VALU, and the B-read Bs[kk][tx*8] (32B stride, 16 lanes) is a 4-way bank
// conflict -> ~992 cyc -> VALUBusy 52-58% as measured (1.17e8 conflict cyc
// = 17% of wall). THIS ROUND: swizzle B columns col' = col + 4*(col>>5)
// (row stride 144) -> read conflicts ~2-way (free); writes stay <=4-way.

__device__ __forceinline__ int bswz(int col) { return col + 4 * (col >> 5); }

struct FragT { float4 a0, a1, a2, a3, b0, b1, b2, b3; };

__device__ __forceinline__ void loadT(const float* pA, const float* pB, FragT& f) {
    f.a0 = *(const float4*)(pA);
    f.a1 = *(const float4*)(pA + (size_t)32 * DIM);
    f.a2 = *(const float4*)(pA + (size_t)64 * DIM);
    f.a3 = *(const float4*)(pA + (size_t)96 * DIM);
    f.b0 = *(const float4*)(pB);
    f.b1 = *(const float4*)(pB + (size_t)32 * DIM);
    f.b2 = *(const float4*)(pB + (size_t)64 * DIM);
    f.b3 = *(const float4*)(pB + (size_t)96 * DIM);
}

__device__ __forceinline__ void storeT(const FragT& f, float (*As)[PAD], float (*Bs)[PB2],
                                       int kq, int r0) {
    const int c0 = kq * 4;
#pragma unroll
    for (int i = 0; i < 4; ++i) {
        const float4 v = (i == 0) ? f.a0 : (i == 1) ? f.a1 : (i == 2) ? f.a2 : f.a3;
        const int r = r0 + 32 * i;
        As[c0 + 0][r] = v.x; As[c0 + 1][r] = v.y;
        As[c0 + 2][r] = v.z; As[c0 + 3][r] = v.w;
    }
#pragma unroll
    for (int i = 0; i < 4; ++i) {
        const float4 v = (i == 0) ? f.b0 : (i == 1) ? f.b1 : (i == 2) ? f.b2 : f.b3;
        const int c = r0 + 36 * i;             // bswz(r0 + 32*i) = r0 + 36*i
        Bs[c0 + 0][c] = v.x; Bs[c0 + 1][c] = v.y;
        Bs[c0 + 2][c] = v.z; Bs[c0 + 3][c] = v.w;
    }
}

__device__ __forceinline__ void computeT(const float (*As)[PAD], const float (*Bs)[PB2],
                                         int tx, int ty, int bb, float (&acc)[8][8]) {
#pragma unroll
    for (int kk = 0; kk < 32; ++kk) {
        const float4 a0 = *(const float4*)&As[kk][ty * 8];
        const float4 a1 = *(const float4*)&As[kk][ty * 8 + 4];
        const float4 b0 = *(const float4*)&Bs[kk][bb];
        const float4 b1 = *(const float4*)&Bs[kk][bb + 4];
        const float a[8] = {a0.x, a0.y, a0.z, a0.w, a1.x, a1.y, a1.z, a1.w};
        const float b[8] = {b0.x, b0.y, b0.z, b0.w, b1.x, b1.y, b1.z, b1.w};
#pragma unroll
        for (int i = 0; i < 8; ++i)
#pragma unroll
            for (int j = 0; j < 8; ++j)
                acc[i][j] = fmaf(a[i], b[j], acc[i][j]);
    }
}

// ---------------- K1: y = X @ Pi^T ; argmin -> idxf + idx8 ----------------
__global__ __launch_bounds__(512) void k1_rot_quant(
    const float* __restrict__ X, const float* __restrict__ Pi, const float* __restrict__ C,
    float* __restrict__ idxf, unsigned char* __restrict__ idx8)
{
    __shared__ float lds[LDSF];
    const int tid = threadIdx.x, pan = tid >> 8, pt = tid & 255;
    float (*As)[PAD] = (float(*)[PAD])(lds + pan * 32 * PAD);
    float (*Bs)[PB2] = (float(*)[PB2])(lds + 2 * 32 * PAD + pan * 32 * PB2);
    const int tx = pt & 15, ty = pt >> 4;
    const int bb = bswz(tx * 8);
    const int kq = pt & 7, r0 = pt >> 3;
    const int m0 = blockIdx.y * 128, n0 = blockIdx.x * 128;
    const float* pA = X  + (size_t)(m0 + r0) * DIM + pan * 512 + kq * 4;
    const float* pB = Pi + (size_t)(n0 + r0) * DIM + pan * 512 + kq * 4;
    float acc[8][8] = {};
    FragT f;
    loadT(pA, pB, f);
    for (int t = 0; t < 16; ++t) {
        __syncthreads();
        storeT(f, As, Bs, kq, r0);
        __syncthreads();
        if (t < 15) loadT(pA + (t + 1) * 32, pB + (t + 1) * 32, f);
        computeT(As, Bs, tx, ty, bb, acc);
    }
    __syncthreads();
    if (pan == 1) {
#pragma unroll
        for (int i = 0; i < 8; ++i)
#pragma unroll
            for (int j = 0; j < 8; ++j)
                lds[(i * 8 + j) * 256 + pt] = acc[i][j];
    }
    __syncthreads();
    if (pan == 0) {
        float c8[8];
#pragma unroll
        for (int t = 0; t < 8; ++t) c8[t] = C[t];
#pragma unroll
        for (int i = 0; i < 8; ++i) {
            const size_t o = (size_t)(m0 + ty * 8 + i) * DIM + n0 + tx * 8;
            float fv[8]; unsigned char bv[8];
#pragma unroll
            for (int j = 0; j < 8; ++j) {
                const float y = acc[i][j] + lds[(i * 8 + j) * 256 + pt];   // fl(p1+p2)
                float best = fabsf(y - c8[0]); int bi = 0;
#pragma unroll
                for (int t2 = 1; t2 < 8; ++t2) {
                    const float d = fabsf(y - c8[t2]);
                    if (d < best) { best = d; bi = t2; }   // strict <: np first-min tie
                }
                fv[j] = (float)bi; bv[j] = (unsigned char)bi;
            }
            *(float4*)&idxf[o]     = make_float4(fv[0], fv[1], fv[2], fv[3]);
            *(float4*)&idxf[o + 4] = make_float4(fv[4], fv[5], fv[6], fv[7]);
            *(uchar4*)&idx8[o]     = make_uchar4(bv[0], bv[1], bv[2], bv[3]);
            *(uchar4*)&idx8[o + 4] = make_uchar4(bv[4], bv[5], bv[6], bv[7]);
        }
    }
}

// ---------------- K3: xhat = yhat @ Pi ; R = X - xhat ; fused norm partials ----------------
__global__ __launch_bounds__(512) void k3_unrot_residual(
    const float* __restrict__ X, const float* __restrict__ Pi, const float* __restrict__ C,
    const unsigned char* __restrict__ idx8, float* __restrict__ R, double* __restrict__ nrm2)
{
    __shared__ float lds[LDSF];
    __shared__ float clut[8];
    const int tid = threadIdx.x, pan = tid >> 8, pt = tid & 255;
    float (*As)[PAD] = (float(*)[PAD])(lds + pan * 32 * PAD);
    float (*Bs)[PB2] = (float(*)[PB2])(lds + 2 * 32 * PAD + pan * 32 * PB2);
    const int tx = pt & 15, ty = pt >> 4;
    const int bb = bswz(tx * 8);
    const int kq = pt & 7, r0 = pt >> 3;
    const int nq = pt & 31, kr0 = pt >> 5;                 // B-staging map (32 k x 128 n)
    const int bcol = nq * 4 + 4 * (nq >> 3);               // bswz(nq*4)
    const int m0 = blockIdx.y * 128, n0 = blockIdx.x * 128;
    if (tid < 8) clut[tid] = C[tid];
    const unsigned char* pA = idx8 + (size_t)(m0 + r0) * DIM + pan * 512 + kq * 4;
    const float*         pB = Pi + (size_t)(pan * 512 + kr0) * DIM + n0 + nq * 4;
    float acc[8][8] = {};
    uchar4 ka[4]; float4 kb[4];
#pragma unroll
    for (int i = 0; i < 4; ++i) ka[i] = *(const uchar4*)(pA + (size_t)(32 * i) * DIM);
#pragma unroll
    for (int i = 0; i < 4; ++i) kb[i] = *(const float4*)(pB + (size_t)(8 * i) * DIM);
    for (int t = 0; t < 16; ++t) {
        __syncthreads();
        {
            const int c0 = kq * 4;
#pragma unroll
            for (int i = 0; i < 4; ++i) {
                const int r = r0 + 32 * i;
                As[c0 + 0][r] = clut[ka[i].x]; As[c0 + 1][r] = clut[ka[i].y];
                As[c0 + 2][r] = clut[ka[i].z]; As[c0 + 3][r] = clut[ka[i].w];
            }
#pragma unroll
            for (int i = 0; i < 4; ++i)
                *(float4*)&Bs[kr0 + 8 * i][bcol] = kb[i];
        }
        __syncthreads();
        if (t < 15) {
#pragma unroll
            for (int i = 0; i < 4; ++i)
                ka[i] = *(const uchar4*)(pA + (t + 1) * 32 + (size_t)(32 * i) * DIM);
#pragma unroll
            for (int i = 0; i < 4; ++i)
                kb[i] = *(const float4*)(pB + (size_t)((t + 1) * 32 + 8 * i) * DIM);
        }
        computeT(As, Bs, tx, ty, bb, acc);
    }
    __syncthreads();
    if (pan == 1) {
#pragma unroll
        for (int i = 0; i < 8; ++i)
#pragma unroll
            for (int j = 0; j < 8; ++j)
                lds[(i * 8 + j) * 256 + pt] = acc[i][j];
    }
    __syncthreads();
    if (pan == 0) {
#pragma unroll
        for (int i = 0; i < 8; ++i) {
            const int row = m0 + ty * 8 + i;
            const size_t o = (size_t)row * DIM + n0 + tx * 8;
            const float4 x0 = *(const float4*)&X[o];
            const float4 x1 = *(const float4*)&X[o + 4];
            float rv[8];
            rv[0] = x0.x - (acc[i][0] + lds[(i * 8 + 0) * 256 + pt]);
            rv[1] = x0.y - (acc[i][1] + lds[(i * 8 + 1) * 256 + pt]);
            rv[2] = x0.z - (acc[i][2] + lds[(i * 8 + 2) * 256 + pt]);
            rv[3] = x0.w - (acc[i][3] + lds[(i * 8 + 3) * 256 + pt]);
            rv[4] = x1.x - (acc[i][4] + lds[(i * 8 + 4) * 256 + pt]);
            rv[5] = x1.y - (acc[i][5] + lds[(i * 8 + 5) * 256 + pt]);
            rv[6] = x1.z - (acc[i][6] + lds[(i * 8 + 6) * 256 + pt]);
            rv[7] = x1.w - (acc[i][7] + lds[(i * 8 + 7) * 256 + pt]);
            *(float4*)&R[o]     = make_float4(rv[0], rv[1], rv[2], rv[3]);
            *(float4*)&R[o + 4] = make_float4(rv[4], rv[5], rv[6], rv[7]);
            double s = 0.0;
#pragma unroll
            for (int j = 0; j < 8; ++j) s = fma((double)rv[j], (double)rv[j], s);
#pragma unroll
            for (int mask = 1; mask < 16; mask <<= 1) s += __shfl_xor(s, mask, 16);
            if (tx == 0) atomicAdd(&nrm2[row], s);
        }
    }
}

// ---------------- K5: P = R @ S^T ; sign ----------------
__global__ __launch_bounds__(512) void k5_qjl(
    const float* __restrict__ R, const float* __restrict__ S, float* __restrict__ sgn)
{
    __shared__ float lds[LDSF];
    const int tid = threadIdx.x, pan = tid >> 8, pt = tid & 255;
    float (*As)[PAD] = (float(*)[PAD])(lds + pan * 32 * PAD);
    float (*Bs)[PB2] = (float(*)[PB2])(lds + 2 * 32 * PAD + pan * 32 * PB2);
    const int tx = pt & 15, ty = pt >> 4;
    const int bb = bswz(tx * 8);
    const int kq = pt & 7, r0 = pt >> 3;
    const int m0 = blockIdx.y * 128, n0 = blockIdx.x * 128;
    const float* pA = R + (size_t)(m0 + r0) * DIM + pan * 512 + kq * 4;
    const float* pB = S + (size_t)(n0 + r0) * DIM + pan * 512 + kq * 4;
    float acc[8][8] = {};
    FragT f;
    loadT(pA, pB, f);
    for (int t = 0; t < 16; ++t) {
        __syncthreads();
        storeT(f, As, Bs, kq, r0);
        __syncthreads();
        if (t < 15) loadT(pA + (t + 1) * 32, pB + (t + 1) * 32, f);
        computeT(As, Bs, tx, ty, bb, acc);
    }
    __syncthreads();
    if (pan == 1) {
#pragma unroll
        for (int i = 0; i < 8; ++i)
#pragma unroll
            for (int j = 0; j < 8; ++j)
                lds[(i * 8 + j) * 256 + pt] = acc[i][j];
    }
    __syncthreads();
    if (pan == 0) {
#pragma unroll
        for (int i = 0; i < 8; ++i) {
            const size_t o = (size_t)(m0 + ty * 8 + i) * DIM + n0 + tx * 8;
            float pv[8];
#pragma unroll
            for (int j = 0; j < 8; ++j) pv[j] = acc[i][j] + lds[(i * 8 + j) * 256 + pt];
            *(float4*)&sgn[o]     = make_float4((pv[0] >= 0.f) ? 1.f : -1.f, (pv[1] >= 0.f) ? 1.f : -1.f,
                                                (pv[2] >= 0.f) ? 1.f : -1.f, (pv[3] >= 0.f) ? 1.f : -1.f);
            *(float4*)&sgn[o + 4] = make_float4((pv[4] >= 0.f) ? 1.f : -1.f, (pv[5] >= 0.f) ? 1.f : -1.f,
                                                (pv[6] >= 0.f) ? 1.f : -1.f, (pv[7] >= 0.f) ? 1.f : -1.f);
        }
    }
}

// ---------------- KN: norms = sqrt(nrm2) ----------------
__global__ __launch_bounds__(256) void kN_sqrt(const double* __restrict__ nrm2, float* __restrict__ nrm)
{
    const int i = blockIdx.x * 256 + threadIdx.x;
    if (i < B_ROWS) nrm[i] = (float)sqrt(nrm2[i]);
}

extern "C" void kernel_launch(void* const* d_in, const int* in_sizes, int n_in,
                              void* d_out, int out_size, void* d_ws, size_t ws_size,
                              hipStream_t stream) {
    const float* X  = (const float*)d_in[0];
    const float* Pi = (const float*)d_in[1];
    const float* C  = (const float*)d_in[2];
    const float* S  = (const float*)d_in[3];

    float* out  = (float*)d_out;
    float* idxf = out;                                   // B*D (index values)
    float* sgn  = out + (size_t)B_ROWS * DIM;            // B*D (+-1)
    float* nrm  = sgn + (size_t)B_ROWS * DIM;            // B

    char* ws = (char*)d_ws;
    float*         R    = (float*)ws;                                          // 128 MiB
    unsigned char* idx8 = (unsigned char*)(ws + (size_t)B_ROWS * DIM * 4);     //  32 MiB
    double*        nrm2 = (double*)(ws + (size_t)B_ROWS * DIM * 5);            // 256 KiB

    hipMemsetAsync(nrm2, 0, (size_t)B_ROWS * sizeof(double), stream);

    dim3 blk(512);
    dim3 gG(DIM / 128, B_ROWS / 128);                    // 8 x 256 = 2048 blocks

    k1_rot_quant     <<<gG, blk, 0, stream>>>(X, Pi, C, idxf, idx8);
    k3_unrot_residual<<<gG, blk, 0, stream>>>(X, Pi, C, idx8, R, nrm2);
    kN_sqrt          <<<dim3(B_ROWS / 256), dim3(256), 0, stream>>>(nrm2, nrm);
    k5_qjl           <<<gG, blk, 0, stream>>>(R, S, sgn);
}

// Round 18
// 2727.833 us; speedup vs baseline: 1.0728x; 1.0728x over previous
//
#include <hip/hip_runtime.h>
#include <math.h>

#define B_ROWS 32768
#define DIM    1024
#define PAD    140             // stride ≡ 12 (mod 32); col' = col + 4*(row>>3) ≤ 139
#define LDSF   (2*2*32*PAD)    // 17920 floats = 71.7 KB (≥ 16384 exchange floats)

// Numerics contract (verified r10-r17, absmax 0.0): BLIS sgemm, KC=512.
// Per C element: p1 = serial ascending FMA chain k=0..511, p2 = k=512..1023,
// C = fl(p1+p2). Panels split across the two 256-thread halves of a
// 512-thread block; combined via LDS exchange at the end.
//
// Bank algebra (r17 lesson: fix BOTH sides): stride 140 ≡ 12 mod 32,
// storage col' = logical_col + 4*(row>>3).
//   writes: bank ≡ 16(kq&1)+4(kq>>1)+12j+r0 -> kq gives 8 distinct -> ≤2-way.
//   B reads at cols {tx*4, 64+tx*4}: banks 4tx -> 2-way. A reads: broadcast, free.
// Shift 4*(kk>>3) is a compile-time constant per unrolled kk (no VGPR cost).

struct FragT { float4 a0, a1, a2, a3, b0, b1, b2, b3; };

__device__ __forceinline__ void loadT(const float* pA, const float* pB, FragT& f) {
    f.a0 = *(const float4*)(pA);
    f.a1 = *(const float4*)(pA + (size_t)32 * DIM);
    f.a2 = *(const float4*)(pA + (size_t)64 * DIM);
    f.a3 = *(const float4*)(pA + (size_t)96 * DIM);
    f.b0 = *(const float4*)(pB);
    f.b1 = *(const float4*)(pB + (size_t)32 * DIM);
    f.b2 = *(const float4*)(pB + (size_t)64 * DIM);
    f.b3 = *(const float4*)(pB + (size_t)96 * DIM);
}

__device__ __forceinline__ void storeT(const FragT& f, float (*As)[PAD], float (*Bs)[PAD],
                                       int kq, int r0) {
    const int c0 = kq * 4;
    const int sh = 4 * (kq >> 1);          // = 4*((c0+j)>>3) for j<4
#pragma unroll
    for (int i = 0; i < 4; ++i) {
        const float4 v = (i == 0) ? f.a0 : (i == 1) ? f.a1 : (i == 2) ? f.a2 : f.a3;
        const int col = r0 + 32 * i + sh;
        As[c0 + 0][col] = v.x; As[c0 + 1][col] = v.y;
        As[c0 + 2][col] = v.z; As[c0 + 3][col] = v.w;
    }
#pragma unroll
    for (int i = 0; i < 4; ++i) {
        const float4 v = (i == 0) ? f.b0 : (i == 1) ? f.b1 : (i == 2) ? f.b2 : f.b3;
        const int col = r0 + 32 * i + sh;
        Bs[c0 + 0][col] = v.x; Bs[c0 + 1][col] = v.y;
        Bs[c0 + 2][col] = v.z; Bs[c0 + 3][col] = v.w;
    }
}

__device__ __forceinline__ void computeT(const float (*As)[PAD], const float (*Bs)[PAD],
                                         int tx, int ty, float (&acc)[8][8]) {
#pragma unroll
    for (int kk = 0; kk < 32; ++kk) {
        const int sh = 4 * (kk >> 3);      // compile-time const per unrolled kk
        const float4 a0 = *(const float4*)&As[kk][ty * 8 + sh];
        const float4 a1 = *(const float4*)&As[kk][ty * 8 + 4 + sh];
        const float4 b0 = *(const float4*)&Bs[kk][tx * 4 + sh];
        const float4 b1 = *(const float4*)&Bs[kk][tx * 4 + 64 + sh];
        const float a[8] = {a0.x, a0.y, a0.z, a0.w, a1.x, a1.y, a1.z, a1.w};
        const float b[8] = {b0.x, b0.y, b0.z, b0.w, b1.x, b1.y, b1.z, b1.w};
#pragma unroll
        for (int i = 0; i < 8; ++i)
#pragma unroll
            for (int j = 0; j < 8; ++j)
                acc[i][j] = fmaf(a[i], b[j], acc[i][j]);
    }
}

// ---------------- K1: y = X @ Pi^T ; argmin -> idxf + idx8 ----------------
__global__ __launch_bounds__(512) void k1_rot_quant(
    const float* __restrict__ X, const float* __restrict__ Pi, const float* __restrict__ C,
    float* __restrict__ idxf, unsigned char* __restrict__ idx8)
{
    __shared__ float lds[LDSF];
    const int tid = threadIdx.x, pan = tid >> 8, pt = tid & 255;
    float (*As)[PAD] = (float(*)[PAD])(lds + pan * 32 * PAD);
    float (*Bs)[PAD] = (float(*)[PAD])(lds + 2 * 32 * PAD + pan * 32 * PAD);
    const int tx = pt & 15, ty = pt >> 4;
    const int kq = pt & 7, r0 = pt >> 3;
    const int m0 = blockIdx.y * 128, n0 = blockIdx.x * 128;
    const float* pA = X  + (size_t)(m0 + r0) * DIM + pan * 512 + kq * 4;
    const float* pB = Pi + (size_t)(n0 + r0) * DIM + pan * 512 + kq * 4;
    float acc[8][8] = {};
    FragT f;
    loadT(pA, pB, f);
    for (int t = 0; t < 16; ++t) {
        __syncthreads();
        storeT(f, As, Bs, kq, r0);
        __syncthreads();
        if (t < 15) loadT(pA + (t + 1) * 32, pB + (t + 1) * 32, f);
        computeT(As, Bs, tx, ty, acc);
    }
    __syncthreads();
    if (pan == 1) {
#pragma unroll
        for (int i = 0; i < 8; ++i)
#pragma unroll
            for (int j = 0; j < 8; ++j)
                lds[(i * 8 + j) * 256 + pt] = acc[i][j];
    }
    __syncthreads();
    if (pan == 0) {
        float c8[8];
#pragma unroll
        for (int t = 0; t < 8; ++t) c8[t] = C[t];
#pragma unroll
        for (int i = 0; i < 8; ++i) {
            const size_t o = (size_t)(m0 + ty * 8 + i) * DIM + n0 + tx * 4;
            float fv[8]; unsigned char bv[8];
#pragma unroll
            for (int j = 0; j < 8; ++j) {
                const float y = acc[i][j] + lds[(i * 8 + j) * 256 + pt];   // fl(p1+p2)
                float best = fabsf(y - c8[0]); int bi = 0;
#pragma unroll
                for (int t2 = 1; t2 < 8; ++t2) {
                    const float d = fabsf(y - c8[t2]);
                    if (d < best) { best = d; bi = t2; }   // strict <: np first-min tie
                }
                fv[j] = (float)bi; bv[j] = (unsigned char)bi;
            }
            *(float4*)&idxf[o]      = make_float4(fv[0], fv[1], fv[2], fv[3]);
            *(float4*)&idxf[o + 64] = make_float4(fv[4], fv[5], fv[6], fv[7]);
            *(uchar4*)&idx8[o]      = make_uchar4(bv[0], bv[1], bv[2], bv[3]);
            *(uchar4*)&idx8[o + 64] = make_uchar4(bv[4], bv[5], bv[6], bv[7]);
        }
    }
}

// ---------------- K3: xhat = yhat @ Pi ; R = X - xhat ; fused norm partials ----------------
__global__ __launch_bounds__(512) void k3_unrot_residual(
    const float* __restrict__ X, const float* __restrict__ Pi, const float* __restrict__ C,
    const unsigned char* __restrict__ idx8, float* __restrict__ R, double* __restrict__ nrm2)
{
    __shared__ float lds[LDSF];
    __shared__ float clut[8];
    const int tid = threadIdx.x, pan = tid >> 8, pt = tid & 255;
    float (*As)[PAD] = (float(*)[PAD])(lds + pan * 32 * PAD);
    float (*Bs)[PAD] = (float(*)[PAD])(lds + 2 * 32 * PAD + pan * 32 * PAD);
    const int tx = pt & 15, ty = pt >> 4;
    const int kq = pt & 7, r0 = pt >> 3;
    const int nq = pt & 31, kr0 = pt >> 5;                 // B-staging map (32 k x 128 n)
    const int m0 = blockIdx.y * 128, n0 = blockIdx.x * 128;
    if (tid < 8) clut[tid] = C[tid];
    const unsigned char* pA = idx8 + (size_t)(m0 + r0) * DIM + pan * 512 + kq * 4;
    const float*         pB = Pi + (size_t)(pan * 512 + kr0) * DIM + n0 + nq * 4;
    float acc[8][8] = {};
    uchar4 ka[4]; float4 kb[4];
#pragma unroll
    for (int i = 0; i < 4; ++i) ka[i] = *(const uchar4*)(pA + (size_t)(32 * i) * DIM);
#pragma unroll
    for (int i = 0; i < 4; ++i) kb[i] = *(const float4*)(pB + (size_t)(8 * i) * DIM);
    for (int t = 0; t < 16; ++t) {
        __syncthreads();
        {
            const int c0 = kq * 4;
            const int sh = 4 * (kq >> 1);
#pragma unroll
            for (int i = 0; i < 4; ++i) {
                const int col = r0 + 32 * i + sh;
                As[c0 + 0][col] = clut[ka[i].x]; As[c0 + 1][col] = clut[ka[i].y];
                As[c0 + 2][col] = clut[ka[i].z]; As[c0 + 3][col] = clut[ka[i].w];
            }
#pragma unroll
            for (int i = 0; i < 4; ++i)
                *(float4*)&Bs[kr0 + 8 * i][nq * 4 + 4 * i] = kb[i];   // col' = n + 4*(row>>3), row>>3 = i
        }
        __syncthreads();
        if (t < 15) {
#pragma unroll
            for (int i = 0; i < 4; ++i)
                ka[i] = *(const uchar4*)(pA + (t + 1) * 32 + (size_t)(32 * i) * DIM);
#pragma unroll
            for (int i = 0; i < 4; ++i)
                kb[i] = *(const float4*)(pB + (size_t)((t + 1) * 32 + 8 * i) * DIM);
        }
        computeT(As, Bs, tx, ty, acc);
    }
    __syncthreads();
    if (pan == 1) {
#pragma unroll
        for (int i = 0; i < 8; ++i)
#pragma unroll
            for (int j = 0; j < 8; ++j)
                lds[(i * 8 + j) * 256 + pt] = acc[i][j];
    }
    __syncthreads();
    if (pan == 0) {
#pragma unroll
        for (int i = 0; i < 8; ++i) {
            const int row = m0 + ty * 8 + i;
            const size_t o = (size_t)row * DIM + n0 + tx * 4;
            const float4 x0 = *(const float4*)&X[o];
            const float4 x1 = *(const float4*)&X[o + 64];
            float rv[8];
            rv[0] = x0.x - (acc[i][0] + lds[(i * 8 + 0) * 256 + pt]);
            rv[1] = x0.y - (acc[i][1] + lds[(i * 8 + 1) * 256 + pt]);
            rv[2] = x0.z - (acc[i][2] + lds[(i * 8 + 2) * 256 + pt]);
            rv[3] = x0.w - (acc[i][3] + lds[(i * 8 + 3) * 256 + pt]);
            rv[4] = x1.x - (acc[i][4] + lds[(i * 8 + 4) * 256 + pt]);
            rv[5] = x1.y - (acc[i][5] + lds[(i * 8 + 5) * 256 + pt]);
            rv[6] = x1.z - (acc[i][6] + lds[(i * 8 + 6) * 256 + pt]);
            rv[7] = x1.w - (acc[i][7] + lds[(i * 8 + 7) * 256 + pt]);
            *(float4*)&R[o]      = make_float4(rv[0], rv[1], rv[2], rv[3]);
            *(float4*)&R[o + 64] = make_float4(rv[4], rv[5], rv[6], rv[7]);
            double s = 0.0;
#pragma unroll
            for (int j = 0; j < 8; ++j) s = fma((double)rv[j], (double)rv[j], s);
#pragma unroll
            for (int mask = 1; mask < 16; mask <<= 1) s += __shfl_xor(s, mask, 16);
            if (tx == 0) atomicAdd(&nrm2[row], s);
        }
    }
}

// ---------------- K5: P = R @ S^T ; sign ----------------
__global__ __launch_bounds__(512) void k5_qjl(
    const float* __restrict__ R, const float* __restrict__ S, float* __restrict__ sgn)
{
    __shared__ float lds[LDSF];
    const int tid = threadIdx.x, pan = tid >> 8, pt = tid & 255;
    float (*As)[PAD] = (float(*)[PAD])(lds + pan * 32 * PAD);
    float (*Bs)[PAD] = (float(*)[PAD])(lds + 2 * 32 * PAD + pan * 32 * PAD);
    const int tx = pt & 15, ty = pt >> 4;
    const int kq = pt & 7, r0 = pt >> 3;
    const int m0 = blockIdx.y * 128, n0 = blockIdx.x * 128;
    const float* pA = R + (size_t)(m0 + r0) * DIM + pan * 512 + kq * 4;
    const float* pB = S + (size_t)(n0 + r0) * DIM + pan * 512 + kq * 4;
    float acc[8][8] = {};
    FragT f;
    loadT(pA, pB, f);
    for (int t = 0; t < 16; ++t) {
        __syncthreads();
        storeT(f, As, Bs, kq, r0);
        __syncthreads();
        if (t < 15) loadT(pA + (t + 1) * 32, pB + (t + 1) * 32, f);
        computeT(As, Bs, tx, ty, acc);
    }
    __syncthreads();
    if (pan == 1) {
#pragma unroll
        for (int i = 0; i < 8; ++i)
#pragma unroll
            for (int j = 0; j < 8; ++j)
                lds[(i * 8 + j) * 256 + pt] = acc[i][j];
    }
    __syncthreads();
    if (pan == 0) {
#pragma unroll
        for (int i = 0; i < 8; ++i) {
            const size_t o = (size_t)(m0 + ty * 8 + i) * DIM + n0 + tx * 4;
            float pv[8];
#pragma unroll
            for (int j = 0; j < 8; ++j) pv[j] = acc[i][j] + lds[(i * 8 + j) * 256 + pt];
            *(float4*)&sgn[o]      = make_float4((pv[0] >= 0.f) ? 1.f : -1.f, (pv[1] >= 0.f) ? 1.f : -1.f,
                                                 (pv[2] >= 0.f) ? 1.f : -1.f, (pv[3] >= 0.f) ? 1.f : -1.f);
            *(float4*)&sgn[o + 64] = make_float4((pv[4] >= 0.f) ? 1.f : -1.f, (pv[5] >= 0.f) ? 1.f : -1.f,
                                                 (pv[6] >= 0.f) ? 1.f : -1.f, (pv[7] >= 0.f) ? 1.f : -1.f);
        }
    }
}

// ---------------- KN: norms = sqrt(nrm2) ----------------
__global__ __launch_bounds__(256) void kN_sqrt(const double* __restrict__ nrm2, float* __restrict__ nrm)
{
    const int i = blockIdx.x * 256 + threadIdx.x;
    if (i < B_ROWS) nrm[i] = (float)sqrt(nrm2[i]);
}

extern "C" void kernel_launch(void* const* d_in, const int* in_sizes, int n_in,
                              void* d_out, int out_size, void* d_ws, size_t ws_size,
                              hipStream_t stream) {
    const float* X  = (const float*)d_in[0];
    const float* Pi = (const float*)d_in[1];
    const float* C  = (const float*)d_in[2];
    const float* S  = (const float*)d_in[3];

    float* out  = (float*)d_out;
    float* idxf = out;                                   // B*D (index values)
    float* sgn  = out + (size_t)B_ROWS * DIM;            // B*D (+-1)
    float* nrm  = sgn + (size_t)B_ROWS * DIM;            // B

    char* ws = (char*)d_ws;
    float*         R    = (float*)ws;                                          // 128 MiB
    unsigned char* idx8 = (unsigned char*)(ws + (size_t)B_ROWS * DIM * 4);     //  32 MiB
    double*        nrm2 = (double*)(ws + (size_t)B_ROWS * DIM * 5);            // 256 KiB

    hipMemsetAsync(nrm2, 0, (size_t)B_ROWS * sizeof(double), stream);

    dim3 blk(512);
    dim3 gG(DIM / 128, B_ROWS / 128);                    // 8 x 256 = 2048 blocks

    k1_rot_quant     <<<gG, blk, 0, stream>>>(X, Pi, C, idxf, idx8);
    k3_unrot_residual<<<gG, blk, 0, stream>>>(X, Pi, C, idx8, R, nrm2);
    kN_sqrt          <<<dim3(B_ROWS / 256), dim3(256), 0, stream>>>(nrm2, nrm);
    k5_qjl           <<<gG, blk, 0, stream>>>(R, S, sgn);
}